// Round 7
// baseline (1138.337 us; speedup 1.0000x reference)
//
#include <hip/hip_runtime.h>

// ---------------- problem constants ----------------
constexpr int NPEP = 20000, NMHC = 5000, NTCR = 100000;
constexpr int EPM = 200000, EMT = 400000, BB = 50000;

typedef __attribute__((ext_vector_type(8))) short bf16x8;
typedef __attribute__((ext_vector_type(4))) float f32x4;

__device__ inline ushort f2bf(float x) {
    union { float f; unsigned u; } v; v.f = x;
    unsigned r = (v.u + 0x7FFF + ((v.u >> 16) & 1)) >> 16;
    return (ushort)r;
}
__device__ inline float bf2f(ushort b) {
    union { unsigned u; float f; } t; t.u = ((unsigned)b) << 16; return t.f;
}
__device__ inline void bf2x2(unsigned u, float& a, float& b) {
    union { unsigned x; float f; } t1, t2;
    t1.x = u << 16; t2.x = u & 0xffff0000u;
    a = t1.f; b = t2.f;
}
__device__ inline ushort4 f4bf(float4 v) {
    return make_ushort4(f2bf(v.x), f2bf(v.y), f2bf(v.z), f2bf(v.w));
}

constexpr int RS  = 40;    // mfma LDS row stride
constexpr int RS1 = 136;   // tcr etc tile stride (K=128)
constexpr int RS2 = 264;   // tcr 256-col tile stride

struct SMem {
    union {
        float red[128];
        int ired[256];
        int tsum[256];
        struct { ushort Als[128 * RS]; ushort Wls[128 * RS]; } g;                    // 20480 B
        struct { ushort B[32 * RS2]; ushort A1[32 * RS2]; ushort A2[32 * RS2];
                 int origs[32]; } t;                                                 // 50816 B
    };
};

struct MegaArgs {
    // inputs
    const float *emb_pep, *emb_mhc, *emb_tcr;
    const int *src_pm, *dst_pm, *src_mt, *dst_mt;
    const int *pack_pep, *pack_mhc, *pack_tcr;
    const float *l1_pm_Wl, *l1_pm_bl, *l1_pm_Wr, *l1_mt_Wl, *l1_mt_bl, *l1_mt_Wr;
    const float *l2_pm_Wl, *l2_pm_bl, *l2_pm_Wr, *l2_mt_Wl, *l2_mt_bl, *l2_mt_Wr;
    const float *proj_W, *proj_b, *head_W1, *head_b1, *head_W2, *head_b2;
    float* out;
    // workspace
    int *deg_pm, *cur_pm, *deg_mt, *cur_mt, *mark;
    int *rp_pm, *rp_mt, *csr_pm, *csr_mt;
    int *bsum_pm, *bsum_mt, *bsum_mk, *nrows, *list, *bar;
    float* bp;
    ushort *Wcat1_b, *Wcat2_b, *W1b_b, *W1c_b, *Wcomp_b, *Wr1_b, *Wr2_b;
    ushort *Acat1, *Acat2, *Zb1, *Zb2, *mhc2_b, *Hp_b, *Hm_b, *Ht_b;
};

// ---------------- device-scope grid barrier (monotonic counter) ----------------
__device__ inline void gbar(int* cnt, int target) {
    __syncthreads();
    __threadfence();                       // agent-scope release: L2 writeback (cross-XCD visible)
    if (threadIdx.x == 0) {
        atomicAdd(cnt, 1);                 // device-scope by default
        long long t0 = clock64();
        while (__hip_atomic_load(cnt, __ATOMIC_RELAXED, __HIP_MEMORY_SCOPE_AGENT) < target) {
            __builtin_amdgcn_s_sleep(2);
            if (clock64() - t0 > 2000000000LL) break;   // fail-fast escape (never expected)
        }
    }
    __syncthreads();
    __threadfence();                       // agent-scope acquire: invalidate stale L1/L2
}

// ---------------- mfma tile: dual-output fused GEMM (mhc layers) ----------------
template <int K, int NB0, bool RELU0>
__device__ __forceinline__ void fused_tile(
    SMem& sm, int tid, int bx, int by, int M,
    const ushort* __restrict__ A, const ushort* __restrict__ W,
    const float* __restrict__ bias,
    ushort* __restrict__ out0, int s0, ushort* __restrict__ out1) {
    const int m0 = bx * 128, n0 = by * 128;
    const int lane = tid & 63, w = tid >> 6;
    const int wm = w >> 1, wn = w & 1;
    const int m16 = lane & 15, q = lane >> 4;

    f32x4 acc[4][4] = {};

    for (int k0 = 0; k0 < K; k0 += 32) {
        bf16x8 a_st[2], w_st[2];
#pragma unroll
        for (int r = 0; r < 2; r++) {
            int chunk = tid + r * 256;
            int row = chunk >> 2, off = (chunk & 3) * 8;
            int ga = min(m0 + row, M - 1);
            a_st[r] = *(const bf16x8*)(A + (size_t)ga * K + k0 + off);
            w_st[r] = *(const bf16x8*)(W + (size_t)(n0 + row) * K + k0 + off);
        }
        __syncthreads();
#pragma unroll
        for (int r = 0; r < 2; r++) {
            int chunk = tid + r * 256;
            int row = chunk >> 2, off = (chunk & 3) * 8;
            *(bf16x8*)(&sm.g.Als[row * RS + off]) = a_st[r];
            *(bf16x8*)(&sm.g.Wls[row * RS + off]) = w_st[r];
        }
        __syncthreads();
        bf16x8 af[4], bf[4];
#pragma unroll
        for (int t = 0; t < 4; t++) {
            af[t] = *(const bf16x8*)(&sm.g.Als[(wm * 64 + t * 16 + m16) * RS + q * 8]);
            bf[t] = *(const bf16x8*)(&sm.g.Wls[(wn * 64 + t * 16 + m16) * RS + q * 8]);
        }
#pragma unroll
        for (int mt = 0; mt < 4; mt++)
#pragma unroll
            for (int nt = 0; nt < 4; nt++)
                acc[mt][nt] = __builtin_amdgcn_mfma_f32_16x16x32_bf16(af[mt], bf[nt], acc[mt][nt], 0, 0, 0);
    }

    const bool g1 = (by >= NB0);
#pragma unroll
    for (int mt = 0; mt < 4; mt++) {
#pragma unroll
        for (int i = 0; i < 4; i++) {
            int row = m0 + wm * 64 + mt * 16 + q * 4 + i;
            if (row >= M) continue;
#pragma unroll
            for (int nt = 0; nt < 4; nt++) {
                int col = n0 + wn * 64 + nt * 16 + m16;
                float v = acc[mt][nt][i];
                if (!g1) {
                    v += bias[col];
                    if (RELU0) v = fmaxf(v, 0.f);
                    out0[(size_t)row * s0 + col] = f2bf(v);
                } else {
                    out1[(size_t)row * 256 + (col - NB0 * 128)] = f2bf(v);
                }
            }
        }
    }
}

// ---------------- mfma tile: bf16-out GEMM (Hp / Hm) ----------------
template <int K, bool HASB, bool AF32>
__device__ __forceinline__ void out_tile(
    SMem& sm, int tid, int bx, int by, int M,
    const void* __restrict__ Av, const ushort* __restrict__ W,
    const float* __restrict__ bias, ushort* __restrict__ out) {
    const int m0 = bx * 128, n0 = by * 128;
    const int lane = tid & 63, w = tid >> 6;
    const int wm = w >> 1, wn = w & 1;
    const int m16 = lane & 15, q = lane >> 4;

    f32x4 acc[4][4] = {};

    for (int k0 = 0; k0 < K; k0 += 32) {
        bf16x8 a_st[2], w_st[2];
#pragma unroll
        for (int r = 0; r < 2; r++) {
            int chunk = tid + r * 256;
            int row = chunk >> 2, off = (chunk & 3) * 8;
            int ga = min(m0 + row, M - 1);
            if constexpr (AF32) {
                const float* Af = (const float*)Av;
                float4 f0 = *(const float4*)(Af + (size_t)ga * K + k0 + off);
                float4 f1 = *(const float4*)(Af + (size_t)ga * K + k0 + off + 4);
                ushort4 u0 = f4bf(f0), u1 = f4bf(f1);
                bf16x8 av;
                av[0] = (short)u0.x; av[1] = (short)u0.y; av[2] = (short)u0.z; av[3] = (short)u0.w;
                av[4] = (short)u1.x; av[5] = (short)u1.y; av[6] = (short)u1.z; av[7] = (short)u1.w;
                a_st[r] = av;
            } else {
                a_st[r] = *(const bf16x8*)((const ushort*)Av + (size_t)ga * K + k0 + off);
            }
            w_st[r] = *(const bf16x8*)(W + (size_t)(n0 + row) * K + k0 + off);
        }
        __syncthreads();
#pragma unroll
        for (int r = 0; r < 2; r++) {
            int chunk = tid + r * 256;
            int row = chunk >> 2, off = (chunk & 3) * 8;
            *(bf16x8*)(&sm.g.Als[row * RS + off]) = a_st[r];
            *(bf16x8*)(&sm.g.Wls[row * RS + off]) = w_st[r];
        }
        __syncthreads();
        bf16x8 af[4], bf[4];
#pragma unroll
        for (int t = 0; t < 4; t++) {
            af[t] = *(const bf16x8*)(&sm.g.Als[(wm * 64 + t * 16 + m16) * RS + q * 8]);
            bf[t] = *(const bf16x8*)(&sm.g.Wls[(wn * 64 + t * 16 + m16) * RS + q * 8]);
        }
#pragma unroll
        for (int mt = 0; mt < 4; mt++)
#pragma unroll
            for (int nt = 0; nt < 4; nt++)
                acc[mt][nt] = __builtin_amdgcn_mfma_f32_16x16x32_bf16(af[mt], bf[nt], acc[mt][nt], 0, 0, 0);
    }

#pragma unroll
    for (int mt = 0; mt < 4; mt++) {
#pragma unroll
        for (int i = 0; i < 4; i++) {
            int row = m0 + wm * 64 + mt * 16 + q * 4 + i;
            if (row >= M) continue;
#pragma unroll
            for (int nt = 0; nt < 4; nt++) {
                int col = n0 + wn * 64 + nt * 16 + m16;
                float v = acc[mt][nt][i];
                if (HASB) v += bias[col];
                out[(size_t)row * 256 + col] = f2bf(v);
            }
        }
    }
}

// ---------------- tcr tile: gather + tcr1 + tcr2 + Ht (32 rows) ----------------
__device__ __forceinline__ void tcr_tile(SMem& sm, int tid, int bt, int M, const MegaArgs& a) {
    const int m0 = bt * 32;
    const int lane = tid & 63, w = tid >> 6;
    const int m16 = lane & 15, q = lane >> 4;

    __syncthreads();   // protect LDS vs previous iteration / phase

    if (tid < 32) sm.t.origs[tid] = a.list[min(m0 + tid, M - 1)];

    // ---- stage 0: emb_tcr rows f32->bf16 -> B (RS1) ----
#pragma unroll
    for (int r = 0; r < 4; r++) {
        int chunk = tid + r * 256;
        int row = chunk >> 5, c4 = (chunk & 31) * 4;
        int grow = a.list[min(m0 + row, M - 1)];
        float4 v = *(const float4*)(a.emb_tcr + (size_t)grow * 128 + c4);
        *(ushort4*)(&sm.t.B[row * RS1 + c4]) = f4bf(v);
    }

    // ---- neighbor-mean gather (Zb1/Zb2) -> A1, A2 pre-scaled ----
    {
        const int g = tid >> 5, gl = tid & 31;
        for (int rr = g; rr < 32; rr += 8) {
            int cr = min(m0 + rr, M - 1);
            int orig = a.list[cr];
            int e0 = a.rp_mt[orig], e1 = a.rp_mt[orig + 1];
            float s1[8] = {}, s2[8] = {};
            for (int e = e0; e < e1; e++) {
                int sidx = a.csr_mt[e];
                uint4 u1 = *(const uint4*)(a.Zb1 + (size_t)sidx * 256 + gl * 8);
                uint4 u2 = *(const uint4*)(a.Zb2 + (size_t)sidx * 256 + gl * 8);
                float x, y;
                bf2x2(u1.x, x, y); s1[0] += x; s1[1] += y;
                bf2x2(u1.y, x, y); s1[2] += x; s1[3] += y;
                bf2x2(u1.z, x, y); s1[4] += x; s1[5] += y;
                bf2x2(u1.w, x, y); s1[6] += x; s1[7] += y;
                bf2x2(u2.x, x, y); s2[0] += x; s2[1] += y;
                bf2x2(u2.y, x, y); s2[2] += x; s2[3] += y;
                bf2x2(u2.z, x, y); s2[4] += x; s2[5] += y;
                bf2x2(u2.w, x, y); s2[6] += x; s2[7] += y;
            }
            float es = 1.f / fmaxf((float)(e1 - e0), 1.f);
            uint4 w1, w2;
            w1.x = (unsigned)f2bf(s1[0] * es) | ((unsigned)f2bf(s1[1] * es) << 16);
            w1.y = (unsigned)f2bf(s1[2] * es) | ((unsigned)f2bf(s1[3] * es) << 16);
            w1.z = (unsigned)f2bf(s1[4] * es) | ((unsigned)f2bf(s1[5] * es) << 16);
            w1.w = (unsigned)f2bf(s1[6] * es) | ((unsigned)f2bf(s1[7] * es) << 16);
            w2.x = (unsigned)f2bf(s2[0] * es) | ((unsigned)f2bf(s2[1] * es) << 16);
            w2.y = (unsigned)f2bf(s2[2] * es) | ((unsigned)f2bf(s2[3] * es) << 16);
            w2.z = (unsigned)f2bf(s2[4] * es) | ((unsigned)f2bf(s2[5] * es) << 16);
            w2.w = (unsigned)f2bf(s2[6] * es) | ((unsigned)f2bf(s2[7] * es) << 16);
            *(uint4*)(&sm.t.A1[rr * RS2 + gl * 8]) = w1;
            *(uint4*)(&sm.t.A2[rr * RS2 + gl * 8]) = w2;
        }
    }
    __syncthreads();

    // ---- stage 1a: T1 = relu(etc @ Wr1^T + bl1 + A1) ----
    {
        f32x4 acc[2][4] = {};
        for (int k0 = 0; k0 < 128; k0 += 32) {
            bf16x8 af[2], bf[4];
#pragma unroll
            for (int t = 0; t < 2; t++)
                af[t] = *(const bf16x8*)(&sm.t.B[(t * 16 + m16) * RS1 + k0 + q * 8]);
#pragma unroll
            for (int t = 0; t < 4; t++)
                bf[t] = *(const bf16x8*)(a.Wr1_b + (size_t)(w * 64 + t * 16 + m16) * 128 + k0 + q * 8);
#pragma unroll
            for (int mt = 0; mt < 2; mt++)
#pragma unroll
                for (int nt = 0; nt < 4; nt++)
                    acc[mt][nt] = __builtin_amdgcn_mfma_f32_16x16x32_bf16(af[mt], bf[nt], acc[mt][nt], 0, 0, 0);
        }
        __syncthreads();
#pragma unroll
        for (int mt = 0; mt < 2; mt++)
#pragma unroll
            for (int i = 0; i < 4; i++) {
                int lr = mt * 16 + q * 4 + i;
#pragma unroll
                for (int nt = 0; nt < 4; nt++) {
                    int col = w * 64 + nt * 16 + m16;
                    float v = acc[mt][nt][i] + a.l1_mt_bl[col] + bf2f(sm.t.A1[lr * RS2 + col]);
                    sm.t.B[lr * RS2 + col] = f2bf(fmaxf(v, 0.f));
                }
            }
    }
    __syncthreads();

    // ---- stage 1b: T = relu(T1 @ Wr2^T + bl2 + A2) ----
    {
        f32x4 acc[2][4] = {};
        for (int k0 = 0; k0 < 256; k0 += 32) {
            bf16x8 af[2], bf[4];
#pragma unroll
            for (int t = 0; t < 2; t++)
                af[t] = *(const bf16x8*)(&sm.t.B[(t * 16 + m16) * RS2 + k0 + q * 8]);
#pragma unroll
            for (int t = 0; t < 4; t++)
                bf[t] = *(const bf16x8*)(a.Wr2_b + (size_t)(w * 64 + t * 16 + m16) * 256 + k0 + q * 8);
#pragma unroll
            for (int mt = 0; mt < 2; mt++)
#pragma unroll
                for (int nt = 0; nt < 4; nt++)
                    acc[mt][nt] = __builtin_amdgcn_mfma_f32_16x16x32_bf16(af[mt], bf[nt], acc[mt][nt], 0, 0, 0);
        }
        __syncthreads();
#pragma unroll
        for (int mt = 0; mt < 2; mt++)
#pragma unroll
            for (int i = 0; i < 4; i++) {
                int lr = mt * 16 + q * 4 + i;
#pragma unroll
                for (int nt = 0; nt < 4; nt++) {
                    int col = w * 64 + nt * 16 + m16;
                    float v = acc[mt][nt][i] + a.l2_mt_bl[col] + bf2f(sm.t.A2[lr * RS2 + col]);
                    sm.t.B[lr * RS2 + col] = f2bf(fmaxf(v, 0.f));
                }
            }
    }
    __syncthreads();

    // ---- stage 2: Ht_tile = T @ W1c^T -> B ----
    {
        f32x4 acc[2][4] = {};
        for (int k0 = 0; k0 < 256; k0 += 32) {
            bf16x8 af[2], bf[4];
#pragma unroll
            for (int t = 0; t < 2; t++)
                af[t] = *(const bf16x8*)(&sm.t.B[(t * 16 + m16) * RS2 + k0 + q * 8]);
#pragma unroll
            for (int t = 0; t < 4; t++)
                bf[t] = *(const bf16x8*)(a.W1c_b + (size_t)(w * 64 + t * 16 + m16) * 256 + k0 + q * 8);
#pragma unroll
            for (int mt = 0; mt < 2; mt++)
#pragma unroll
                for (int nt = 0; nt < 4; nt++)
                    acc[mt][nt] = __builtin_amdgcn_mfma_f32_16x16x32_bf16(af[mt], bf[nt], acc[mt][nt], 0, 0, 0);
        }
        __syncthreads();
#pragma unroll
        for (int mt = 0; mt < 2; mt++)
#pragma unroll
            for (int i = 0; i < 4; i++) {
                int lr = mt * 16 + q * 4 + i;
#pragma unroll
                for (int nt = 0; nt < 4; nt++) {
                    int col = w * 64 + nt * 16 + m16;
                    sm.t.B[lr * RS2 + col] = f2bf(acc[mt][nt][i]);
                }
            }
    }
    __syncthreads();

    // coalesced row-wise writeback
#pragma unroll
    for (int r = 0; r < 4; r++) {
        int chunk = tid + r * 256;
        int row = chunk >> 5, c8 = (chunk & 31) * 8;
        if (m0 + row < M)
            *(uint4*)(a.Ht_b + (size_t)sm.t.origs[row] * 256 + c8) = *(const uint4*)(&sm.t.B[row * RS2 + c8]);
    }
}

// ---------------- the persistent mega-kernel (own grid barrier) ----------------
__global__ __launch_bounds__(256, 3) void mega_kernel(MegaArgs a) {
    const int tid = threadIdx.x;
    const int bid = blockIdx.x;
    const int NB = gridDim.x;
    int ep = 0;
    __shared__ SMem sm;

    // ================= P0: prep (zero + weight packs + wcomp) =================
    for (int b = bid; b < 2688; b += NB) {
        if (b < 303) {
            int i = b * 256 + tid;
            if (i < 77500) ((int4*)a.deg_pm)[i] = make_int4(0, 0, 0, 0);  // zeros deg/cur/mark (310000 ints)
        } else if (b < 335) {
            int i = (b - 303) * 256 + tid;
            if (i < 8192) ((ushort4*)a.Wr1_b)[i] = f4bf(((const float4*)a.l1_mt_Wr)[i]);
        } else if (b < 399) {
            int i = (b - 335) * 256 + tid;
            if (i < 16384) ((ushort4*)a.Wr2_b)[i] = f4bf(((const float4*)a.l2_mt_Wr)[i]);
        } else if (b < 463) {
            int i = (b - 399) * 256 + tid;
            if (i < 16384) {
                int n = i >> 6, k4 = (i & 63) * 4;
                ((ushort4*)a.W1b_b)[i] = f4bf(*(const float4*)(a.head_W1 + (size_t)n * 768 + 256 + k4));
            }
        } else if (b < 527) {
            int i = (b - 463) * 256 + tid;
            if (i < 16384) {
                int n = i >> 6, k4 = (i & 63) * 4;
                ((ushort4*)a.W1c_b)[i] = f4bf(*(const float4*)(a.head_W1 + (size_t)n * 768 + 512 + k4));
            }
        } else if (b < 1039) {
            int idx = (b - 527) * 256 + tid;
            if (idx < 131072) {
                int r = idx >> 8, k = idx & 255;
                float v;
                if (r < 256) v = (k < 128) ? a.l1_pm_Wl[r * 128 + k] : a.l1_pm_Wr[r * 128 + (k - 128)];
                else         v = (k < 128) ? 0.f : a.l1_mt_Wl[(r - 256) * 128 + (k - 128)];
                a.Wcat1_b[idx] = f2bf(v);
            }
        } else if (b < 1807) {
            int idx = (b - 1039) * 256 + tid;
            if (idx < 196608) {
                int r = idx / 384, k = idx - r * 384;
                float v;
                if (r < 256) v = (k < 128) ? a.l2_pm_Wl[r * 128 + k] : a.l2_pm_Wr[r * 256 + (k - 128)];
                else         v = (k < 128) ? 0.f : a.l2_mt_Wl[(r - 256) * 256 + (k - 128)];
                a.Wcat2_b[idx] = f2bf(v);
            }
        } else if (b < 2432) {
            int i4 = (b - 1807) * 256 + tid;
            if (i4 < 160000) {
                int r = i4 >> 5, c4 = (i4 & 31) * 4;
                *(ushort4*)(a.Acat1 + (size_t)r * 256 + 128 + c4) = f4bf(((const float4*)a.emb_mhc)[i4]);
            }
        } else {
            int i = b - 2432;   // 0..255
            const float* w1row = a.head_W1 + (size_t)i * 768;
            __syncthreads();
            if (tid < 128) {
                float acc = 0.f;
                for (int k = 0; k < 256; k++) acc += w1row[k] * a.proj_W[k * 128 + tid];
                a.Wcomp_b[i * 128 + tid] = f2bf(acc);
                sm.red[tid] = w1row[2 * tid] * a.proj_b[2 * tid] + w1row[2 * tid + 1] * a.proj_b[2 * tid + 1];
            }
            __syncthreads();
            if (tid < 64) sm.red[tid] += sm.red[tid + 64];
            __syncthreads();
            if (tid < 32) sm.red[tid] += sm.red[tid + 32];
            __syncthreads();
            if (tid == 0) {
                float s = 0.f;
                for (int j = 0; j < 32; j++) s += sm.red[j];
                a.bp[i] = s;
            }
        }
    }
    gbar(a.bar, NB * ++ep);

    // ================= P1: histogram + mark =================
    for (int t = bid * 256 + tid; t < EPM + EMT + BB; t += NB * 256) {
        if (t < EPM) atomicAdd(&a.deg_pm[a.dst_pm[t]], 1);
        else if (t < EPM + EMT) atomicAdd(&a.deg_mt[a.dst_mt[t - EPM]], 1);
        else atomicAdd(&a.mark[a.pack_tcr[t - EPM - EMT]], 0x10000);  // any nonzero marker
    }
    gbar(a.bar, NB * ++ep);

    // ================= P2: block sums (mark: count-nonzero) =================
    for (int b = bid; b < 201; b += NB) {
        const int* deg; int n, bi; int* bsum; int mk = 0;
        if (b < 5) { deg = a.deg_pm; n = NMHC; bi = b; bsum = a.bsum_pm; }
        else if (b < 103) { deg = a.deg_mt; n = NTCR; bi = b - 5; bsum = a.bsum_mt; }
        else { deg = a.mark; n = NTCR; bi = b - 103; bsum = a.bsum_mk; mk = 1; }
        __syncthreads();
        const int base = bi * 1024;
        int s = 0;
#pragma unroll
        for (int j = 0; j < 4; j++) {
            int i = base + tid + j * 256;
            if (i < n) { int d = deg[i]; s += mk ? (d != 0) : d; }
        }
        sm.ired[tid] = s;
        __syncthreads();
        for (int off = 128; off > 0; off >>= 1) {
            if (tid < off) sm.ired[tid] += sm.ired[tid + off];
            __syncthreads();
        }
        if (tid == 0) bsum[bi] = sm.ired[0];
    }
    gbar(a.bar, NB * ++ep);

    // ================= P3: emit (inline exclusive base from raw partials) =================
    for (int b = bid; b < 201; b += NB) {
        const int* deg; const int* bsumA; int* rp; int n, nb, bi, mode;
        if (b < 5) { deg = a.deg_pm; bsumA = a.bsum_pm; rp = a.rp_pm; n = NMHC; nb = 5; bi = b; mode = 0; }
        else if (b < 103) { deg = a.deg_mt; bsumA = a.bsum_mt; rp = a.rp_mt; n = NTCR; nb = 98; bi = b - 5; mode = 0; }
        else { deg = a.mark; bsumA = a.bsum_mk; rp = nullptr; n = NTCR; nb = 98; bi = b - 103; mode = 1; }
        __syncthreads();
        sm.tsum[tid] = (tid < bi) ? bsumA[tid] : 0;
        __syncthreads();
        for (int off = 128; off > 0; off >>= 1) {
            if (tid < off) sm.tsum[tid] += sm.tsum[tid + off];
            __syncthreads();
        }
        const int base = sm.tsum[0];
        __syncthreads();
        const int i0 = bi * 1024 + tid * 4;
        int4 v = make_int4(0, 0, 0, 0);
        if (i0 + 3 < n) v = *(const int4*)(deg + i0);
        else if (i0 < n) {
            int t[4] = {0, 0, 0, 0};
            for (int j = 0; j < 4 && i0 + j < n; j++) t[j] = deg[i0 + j];
            v = make_int4(t[0], t[1], t[2], t[3]);
        }
        if (mode == 1) { v.x = (v.x != 0); v.y = (v.y != 0); v.z = (v.z != 0); v.w = (v.w != 0); }
        sm.tsum[tid] = v.x + v.y + v.z + v.w;
        __syncthreads();
        for (int off = 1; off < 256; off <<= 1) {
            int t = (tid >= off) ? sm.tsum[tid - off] : 0;
            __syncthreads();
            sm.tsum[tid] += t;
            __syncthreads();
        }
        int ex = ((tid > 0) ? sm.tsum[tid - 1] : 0) + base;
        if (mode == 0) {
            if (i0 + 3 < n) {
                int r1 = ex + v.x, r2 = r1 + v.y, r3 = r2 + v.z;
                *(int4*)(rp + i0) = make_int4(ex, r1, r2, r3);
            } else if (i0 < n) {
                int r = ex;
                int vv[4] = {v.x, v.y, v.z, v.w};
                for (int j = 0; j < 4 && i0 + j < n; j++) { rp[i0 + j] = r; r += vv[j]; }
            }
            if (bi == nb - 1 && tid == 255) rp[n] = base + sm.tsum[255];
        } else {
            int p = ex;
            int vv[4] = {v.x, v.y, v.z, v.w};
#pragma unroll
            for (int j = 0; j < 4; j++) {
                if (i0 + j < n && vv[j]) a.list[p++] = i0 + j;
            }
            if (bi == nb - 1 && tid == 255) a.nrows[0] = base + sm.tsum[255];
        }
    }
    gbar(a.bar, NB * ++ep);

    // ================= P4: CSR fill =================
    for (int t = bid * 256 + tid; t < EPM + EMT; t += NB * 256) {
        if (t < EPM) {
            int d = a.dst_pm[t];
            int pos = atomicAdd(&a.cur_pm[d], 1);
            a.csr_pm[a.rp_pm[d] + pos] = a.src_pm[t];
        } else {
            int t2 = t - EPM;
            int d = a.dst_mt[t2];
            int pos = atomicAdd(&a.cur_mt[d], 1);
            a.csr_mt[a.rp_mt[d] + pos] = a.src_mt[t2];
        }
    }
    gbar(a.bar, NB * ++ep);

    // ================= P5: pm gather + mean =================
    for (int vb = bid; vb < 625; vb += NB) {
        const int r = vb * 8 + (tid >> 5);
        const int lane = tid & 31;
        if (r < NMHC) {
            const int e0 = a.rp_pm[r], e1 = a.rp_pm[r + 1];
            float4 s = make_float4(0.f, 0.f, 0.f, 0.f);
            for (int e = e0; e < e1; e++) {
                const int sidx = a.csr_pm[e];
                float4 v = ((const float4*)(a.emb_pep + (long)sidx * 128))[lane];
                s.x += v.x; s.y += v.y; s.z += v.z; s.w += v.w;
            }
            float sc = 1.f / fmaxf((float)(e1 - e0), 1.f);
            ushort4 o = make_ushort4(f2bf(s.x * sc), f2bf(s.y * sc), f2bf(s.z * sc), f2bf(s.w * sc));
            *(ushort4*)(a.Acat1 + (size_t)r * 256 + lane * 4) = o;
            *(ushort4*)(a.Acat2 + (size_t)r * 384 + lane * 4) = o;
        }
    }
    gbar(a.bar, NB * ++ep);

    // ================= P6: mhc layer1 (160) + Hp half (157) =================
    for (int vb = bid; vb < 317; vb += NB) {
        if (vb < 160)
            fused_tile<256, 2, true>(sm, tid, vb % 40, vb / 40, NMHC,
                                     a.Acat1, a.Wcat1_b, a.l1_pm_bl, a.Acat2 + 128, 384, a.Zb1);
        else {
            int v = vb - 160;                        // 0..156 -> Hp tiles by=0
            out_tile<128, true, true>(sm, tid, v % 157, v / 157, NPEP,
                                      a.emb_pep, a.Wcomp_b, a.bp, a.Hp_b);
        }
    }
    gbar(a.bar, NB * ++ep);

    // ================= P7: mhc layer2 (160) + Hp half (157) =================
    for (int vb = bid; vb < 317; vb += NB) {
        if (vb < 160)
            fused_tile<384, 2, true>(sm, tid, vb % 40, vb / 40, NMHC,
                                     a.Acat2, a.Wcat2_b, a.l2_pm_bl, a.mhc2_b, 256, a.Zb2);
        else {
            int v = vb - 160 + 157;                  // 157..313 -> Hp tiles by=1
            out_tile<128, true, true>(sm, tid, v % 157, v / 157, NPEP,
                                      a.emb_pep, a.Wcomp_b, a.bp, a.Hp_b);
        }
    }
    gbar(a.bar, NB * ++ep);

    // ================= P8: tcr chain (grid-stride tiles) + Hm (80) =================
    {
        const int M = a.nrows[0];
        const int NT = (M + 31) >> 5;
        for (int vb = bid; vb < NT + 80; vb += NB) {
            if (vb < NT) tcr_tile(sm, tid, vb, M, a);
            else {
                int v = vb - NT;
                __syncthreads();
                out_tile<256, false, false>(sm, tid, v % 40, v / 40, NMHC,
                                            a.mhc2_b, a.W1b_b, nullptr, a.Hm_b);
            }
        }
    }
    gbar(a.bar, NB * ++ep);

    // ================= P9: combine =================
    {
        const int lane = tid & 63, w = tid >> 6;
        const int c = lane * 4;
        const float4 b1v = *(const float4*)(a.head_b1 + c);
        const float4 w2v = *(const float4*)(a.head_W2 + c);
        const float b2v = a.head_b2[0];
        for (int vb = bid; vb < (BB + 31) / 32; vb += NB) {
            const int base2 = vb * 32 + w * 8;
#pragma unroll
            for (int t = 0; t < 8; t++) {
                int i = base2 + t;
                if (i < BB) {
                    int ra = a.pack_pep[i], rb = a.pack_mhc[i], rc = a.pack_tcr[i];
                    ushort4 ua = *(const ushort4*)(a.Hp_b + (size_t)ra * 256 + c);
                    ushort4 ub = *(const ushort4*)(a.Hm_b + (size_t)rb * 256 + c);
                    ushort4 uc = *(const ushort4*)(a.Ht_b + (size_t)rc * 256 + c);
                    float h0 = fmaxf(bf2f(ua.x) + bf2f(ub.x) + bf2f(uc.x) + b1v.x, 0.f);
                    float h1 = fmaxf(bf2f(ua.y) + bf2f(ub.y) + bf2f(uc.y) + b1v.y, 0.f);
                    float h2 = fmaxf(bf2f(ua.z) + bf2f(ub.z) + bf2f(uc.z) + b1v.z, 0.f);
                    float h3 = fmaxf(bf2f(ua.w) + bf2f(ub.w) + bf2f(uc.w) + b1v.w, 0.f);
                    float p = h0 * w2v.x + h1 * w2v.y + h2 * w2v.z + h3 * w2v.w;
#pragma unroll
                    for (int off = 32; off > 0; off >>= 1) p += __shfl_down(p, off);
                    if (lane == 0) a.out[i] = p + b2v;
                }
            }
        }
    }
}

// ---------------- launch ----------------
extern "C" void kernel_launch(void* const* d_in, const int* in_sizes, int n_in,
                              void* d_out, int out_size, void* d_ws, size_t ws_size,
                              hipStream_t stream) {
    MegaArgs a;
    a.emb_pep = (const float*)d_in[0];
    a.emb_mhc = (const float*)d_in[1];
    a.emb_tcr = (const float*)d_in[2];
    a.src_pm = (const int*)d_in[3];
    a.dst_pm = (const int*)d_in[4];
    a.src_mt = (const int*)d_in[5];
    a.dst_mt = (const int*)d_in[6];
    a.pack_pep = (const int*)d_in[7];
    a.pack_mhc = (const int*)d_in[8];
    a.pack_tcr = (const int*)d_in[9];
    a.l1_pm_Wl = (const float*)d_in[10];
    a.l1_pm_bl = (const float*)d_in[11];
    a.l1_pm_Wr = (const float*)d_in[12];
    a.l1_mt_Wl = (const float*)d_in[13];
    a.l1_mt_bl = (const float*)d_in[14];
    a.l1_mt_Wr = (const float*)d_in[15];
    a.l2_pm_Wl = (const float*)d_in[16];
    a.l2_pm_bl = (const float*)d_in[17];
    a.l2_pm_Wr = (const float*)d_in[18];
    a.l2_mt_Wl = (const float*)d_in[19];
    a.l2_mt_bl = (const float*)d_in[20];
    a.l2_mt_Wr = (const float*)d_in[21];
    a.proj_W = (const float*)d_in[22];
    a.proj_b = (const float*)d_in[23];
    a.head_W1 = (const float*)d_in[24];
    a.head_b1 = (const float*)d_in[25];
    a.head_W2 = (const float*)d_in[26];
    a.head_b2 = (const float*)d_in[27];
    a.out = (float*)d_out;

    // ---------------- workspace layout ----------------
    int* ib = (int*)d_ws;
    a.deg_pm = ib;                  // 5000
    a.cur_pm = ib + 5000;           // 5000
    a.deg_mt = ib + 10000;          // 100000
    a.cur_mt = ib + 110000;         // 100000
    a.mark   = ib + 210000;         // 100000   [zero region: first 310000 ints]
    a.rp_pm  = ib + 310000;         // 5001 (pad 5008)
    a.rp_mt  = ib + 315008;         // 100001 (pad 100008)
    a.csr_pm = ib + 415016;         // 200000
    a.csr_mt = ib + 615016;         // 400000
    a.bsum_pm = ib + 1015016;       // 160
    a.bsum_mt = ib + 1015176;       // 160
    a.bsum_mk = ib + 1015336;       // 160
    a.nrows   = ib + 1015496;       // 8
    a.list    = ib + 1015504;       // 50048 -> ends 1065552
    a.bar     = ib + 1065552;       // 16 -> 1065568

    float* f = (float*)(ib + 1065568);
    a.bp = f;                       // 256

    ushort* u = (ushort*)(f + 256);
    a.Wcat1_b = u;                  // 131072
    a.Wcat2_b = u + 131072;         // 196608
    a.W1b_b   = u + 327680;         // 65536
    a.W1c_b   = u + 393216;         // 65536
    a.Wcomp_b = u + 458752;         // 32768
    a.Wr1_b   = u + 491520;         // 32768
    a.Wr2_b   = u + 524288;         // 65536
    a.Acat1   = u + 589824;         // 1280000
    a.Acat2   = u + 1869824;        // 1920000
    a.Zb1     = u + 3789824;        // 1280000
    a.Zb2     = u + 5069824;        // 1280000
    a.mhc2_b  = u + 6349824;        // 1280000
    a.Hp_b    = u + 7629824;        // 5120000
    a.Hm_b    = u + 12749824;       // 1280000
    a.Ht_b    = u + 14029824;       // 25600000
    // ends at 39629824 ushorts (~84 MB total)

    // grid sized to guaranteed co-residency (persistent-kernel pattern)
    static int nblk = 0;
    if (nblk == 0) {
        int occ = 0, ncu = 0;
        hipDeviceProp_t prop;
        if (hipGetDeviceProperties(&prop, 0) == hipSuccess) ncu = prop.multiProcessorCount;
        if (ncu <= 0) ncu = 256;
        if (hipOccupancyMaxActiveBlocksPerMultiprocessor(&occ, mega_kernel, 256, 0) != hipSuccess || occ <= 0)
            occ = 1;
        if (occ > 3) occ = 3;
        nblk = occ * ncu;
        if (nblk > 768) nblk = 768;
        if (nblk < 8) nblk = 8;
    }

    hipMemsetAsync(a.bar, 0, 16, stream);
    mega_kernel<<<nblk, 256, 0, stream>>>(a);
}

// Round 8
// 385.115 us; speedup vs baseline: 2.9558x; 2.9558x over previous
//
#include <hip/hip_runtime.h>

// ---------------- problem constants ----------------
constexpr int NPEP = 20000, NMHC = 5000, NTCR = 100000;
constexpr int EPM = 200000, EMT = 400000, BB = 50000;
constexpr int MAXU = 50000;

typedef __attribute__((ext_vector_type(8))) short bf16x8;
typedef __attribute__((ext_vector_type(4))) float f32x4;

__device__ inline ushort f2bf(float x) {
    union { float f; unsigned u; } v; v.f = x;
    unsigned r = (v.u + 0x7FFF + ((v.u >> 16) & 1)) >> 16;
    return (ushort)r;
}
__device__ inline float bf2f(ushort b) {
    union { unsigned u; float f; } t; t.u = ((unsigned)b) << 16; return t.f;
}
__device__ inline void bf2x2(unsigned u, float& a, float& b) {
    union { unsigned x; float f; } t1, t2;
    t1.x = u << 16; t2.x = u & 0xffff0000u;
    a = t1.f; b = t2.f;
}
__device__ inline ushort4 f4bf(float4 v) {
    return make_ushort4(f2bf(v.x), f2bf(v.y), f2bf(v.z), f2bf(v.w));
}

constexpr int RS  = 40;    // mfma LDS row stride
constexpr int RS1 = 136;   // tcr etc tile stride (K=128)
constexpr int RS2 = 264;   // tcr 256-col tile stride

// ---------------- shared: bf16-out GEMM tile (Hp / Hm) ----------------
template <int K, bool HASB, bool AF32>
__device__ void out_tile(ushort* Als, ushort* Wls, int tid, int bx, int by, int M,
                         const void* __restrict__ Av, const ushort* __restrict__ W,
                         const float* __restrict__ bias, ushort* __restrict__ out) {
    const int m0 = bx * 128, n0 = by * 128;
    const int lane = tid & 63, w = tid >> 6;
    const int wm = w >> 1, wn = w & 1;
    const int m16 = lane & 15, q = lane >> 4;

    f32x4 acc[4][4] = {};

    for (int k0 = 0; k0 < K; k0 += 32) {
        bf16x8 a_st[2], w_st[2];
#pragma unroll
        for (int r = 0; r < 2; r++) {
            int chunk = tid + r * 256;
            int row = chunk >> 2, off = (chunk & 3) * 8;
            int ga = min(m0 + row, M - 1);
            if constexpr (AF32) {
                const float* Af = (const float*)Av;
                float4 f0 = *(const float4*)(Af + (size_t)ga * K + k0 + off);
                float4 f1 = *(const float4*)(Af + (size_t)ga * K + k0 + off + 4);
                ushort4 u0 = f4bf(f0), u1 = f4bf(f1);
                bf16x8 av;
                av[0] = (short)u0.x; av[1] = (short)u0.y; av[2] = (short)u0.z; av[3] = (short)u0.w;
                av[4] = (short)u1.x; av[5] = (short)u1.y; av[6] = (short)u1.z; av[7] = (short)u1.w;
                a_st[r] = av;
            } else {
                a_st[r] = *(const bf16x8*)((const ushort*)Av + (size_t)ga * K + k0 + off);
            }
            w_st[r] = *(const bf16x8*)(W + (size_t)(n0 + row) * K + k0 + off);
        }
        __syncthreads();
#pragma unroll
        for (int r = 0; r < 2; r++) {
            int chunk = tid + r * 256;
            int row = chunk >> 2, off = (chunk & 3) * 8;
            *(bf16x8*)(&Als[row * RS + off]) = a_st[r];
            *(bf16x8*)(&Wls[row * RS + off]) = w_st[r];
        }
        __syncthreads();
        bf16x8 af[4], bf[4];
#pragma unroll
        for (int t = 0; t < 4; t++) {
            af[t] = *(const bf16x8*)(&Als[(wm * 64 + t * 16 + m16) * RS + q * 8]);
            bf[t] = *(const bf16x8*)(&Wls[(wn * 64 + t * 16 + m16) * RS + q * 8]);
        }
#pragma unroll
        for (int mt = 0; mt < 4; mt++)
#pragma unroll
            for (int nt = 0; nt < 4; nt++)
                acc[mt][nt] = __builtin_amdgcn_mfma_f32_16x16x32_bf16(af[mt], bf[nt], acc[mt][nt], 0, 0, 0);
    }

#pragma unroll
    for (int mt = 0; mt < 4; mt++) {
#pragma unroll
        for (int i = 0; i < 4; i++) {
            int row = m0 + wm * 64 + mt * 16 + q * 4 + i;
            if (row >= M) continue;
#pragma unroll
            for (int nt = 0; nt < 4; nt++) {
                int col = n0 + wn * 64 + nt * 16 + m16;
                float v = acc[mt][nt][i];
                if (HASB) v += bias[col];
                out[(size_t)row * 256 + col] = f2bf(v);
            }
        }
    }
}

// ---------------- merged prep kernel (block-range dispatch) ----------------
__global__ __launch_bounds__(256) void prep_kernel(
    int* __restrict__ ibz,
    const float4* __restrict__ Wr1f, ushort4* __restrict__ Wr1_b,
    const float4* __restrict__ Wr2f, ushort4* __restrict__ Wr2_b,
    const float* __restrict__ head_W1, ushort4* __restrict__ W1b_b, ushort4* __restrict__ W1c_b,
    const float* __restrict__ l1_pm_Wl, const float* __restrict__ l1_pm_Wr,
    const float* __restrict__ l1_mt_Wl, ushort* __restrict__ Wcat1_b,
    const float* __restrict__ l2_pm_Wl, const float* __restrict__ l2_pm_Wr,
    const float* __restrict__ l2_mt_Wl, ushort* __restrict__ Wcat2_b,
    const float4* __restrict__ emb_mhc, ushort* __restrict__ Acat1,
    const float* __restrict__ proj_W, const float* __restrict__ proj_b,
    ushort* __restrict__ Wcomp_b, float* __restrict__ bp) {
    __shared__ float red[128];
    const int b = blockIdx.x, tid = threadIdx.x;
    if (b < 303) {
        int i = b * 256 + tid;
        if (i < 77500) ((int4*)ibz)[i] = make_int4(0, 0, 0, 0);   // 310000 ints zeroed
    } else if (b < 335) {
        int i = (b - 303) * 256 + tid;
        if (i < 8192) Wr1_b[i] = f4bf(Wr1f[i]);
    } else if (b < 399) {
        int i = (b - 335) * 256 + tid;
        if (i < 16384) Wr2_b[i] = f4bf(Wr2f[i]);
    } else if (b < 463) {
        int i = (b - 399) * 256 + tid;
        if (i < 16384) {
            int n = i >> 6, k4 = (i & 63) * 4;
            W1b_b[i] = f4bf(*(const float4*)(head_W1 + (size_t)n * 768 + 256 + k4));
        }
    } else if (b < 527) {
        int i = (b - 463) * 256 + tid;
        if (i < 16384) {
            int n = i >> 6, k4 = (i & 63) * 4;
            W1c_b[i] = f4bf(*(const float4*)(head_W1 + (size_t)n * 768 + 512 + k4));
        }
    } else if (b < 1039) {
        int idx = (b - 527) * 256 + tid;   // 512x256
        if (idx < 131072) {
            int r = idx >> 8, k = idx & 255;
            float v;
            if (r < 256) v = (k < 128) ? l1_pm_Wl[r * 128 + k] : l1_pm_Wr[r * 128 + (k - 128)];
            else         v = (k < 128) ? 0.f : l1_mt_Wl[(r - 256) * 128 + (k - 128)];
            Wcat1_b[idx] = f2bf(v);
        }
    } else if (b < 1807) {
        int idx = (b - 1039) * 256 + tid;   // 512x384
        if (idx < 196608) {
            int r = idx / 384, k = idx - r * 384;
            float v;
            if (r < 256) v = (k < 128) ? l2_pm_Wl[r * 128 + k] : l2_pm_Wr[r * 256 + (k - 128)];
            else         v = (k < 128) ? 0.f : l2_mt_Wl[(r - 256) * 256 + (k - 128)];
            Wcat2_b[idx] = f2bf(v);
        }
    } else if (b < 2432) {
        int i4 = (b - 1807) * 256 + tid;
        if (i4 < 160000) {
            int r = i4 >> 5, c4 = (i4 & 31) * 4;
            *(ushort4*)(Acat1 + (size_t)r * 256 + 128 + c4) = f4bf(emb_mhc[i4]);
        }
    } else {
        // wcomp: one block per output row i (0..255)
        int i = b - 2432;
        const float* w1row = head_W1 + (size_t)i * 768;
        if (tid < 128) {
            float acc = 0.f;
            for (int k = 0; k < 256; k++) acc += w1row[k] * proj_W[k * 128 + tid];
            Wcomp_b[i * 128 + tid] = f2bf(acc);
            red[tid] = w1row[2 * tid] * proj_b[2 * tid] + w1row[2 * tid + 1] * proj_b[2 * tid + 1];
        }
        __syncthreads();
        if (tid < 64) { red[tid] += red[tid + 64]; }
        __syncthreads();
        if (tid < 32) { red[tid] += red[tid + 32]; }
        __syncthreads();
        if (tid == 0) {
            float s = 0.f;
            for (int j = 0; j < 32; j++) s += red[j];
            bp[i] = s;
        }
    }
}

// ---------------- merged histogram + tcr row marking ----------------
__global__ void hist2_kernel(const int* __restrict__ dst_pm, const int* __restrict__ dst_mt,
                             const int* __restrict__ pack_tcr,
                             int* __restrict__ deg_pm, int* __restrict__ deg_mt,
                             int* __restrict__ mark) {
    int t = blockIdx.x * blockDim.x + threadIdx.x;
    if (t < EPM) atomicAdd(&deg_pm[dst_pm[t]], 1);
    else if (t < EPM + EMT) atomicAdd(&deg_mt[dst_mt[t - EPM]], 1);
    else if (t < EPM + EMT + BB) mark[pack_tcr[t - EPM - EMT]] = 1;  // benign race
}

// ---------------- merged blocksum ----------------
__global__ __launch_bounds__(256) void blocksum2_kernel(const int* __restrict__ deg_pm,
                                                        const int* __restrict__ deg_mt,
                                                        const int* __restrict__ mark,
                                                        int* __restrict__ bsum_pm,
                                                        int* __restrict__ bsum_mt,
                                                        int* __restrict__ bsum_mk) {
    __shared__ int red[256];
    const int tid = threadIdx.x;
    const int* deg; int n, bi; int* bsum;
    if (blockIdx.x < 5) { deg = deg_pm; n = NMHC; bi = blockIdx.x; bsum = bsum_pm; }
    else if (blockIdx.x < 103) { deg = deg_mt; n = NTCR; bi = blockIdx.x - 5; bsum = bsum_mt; }
    else { deg = mark; n = NTCR; bi = blockIdx.x - 103; bsum = bsum_mk; }
    const int base = bi * 1024;
    int s = 0;
#pragma unroll
    for (int j = 0; j < 4; j++) {
        int i = base + tid + j * 256;
        if (i < n) s += deg[i];
    }
    red[tid] = s;
    __syncthreads();
    for (int off = 128; off > 0; off >>= 1) {
        if (tid < off) red[tid] += red[tid + off];
        __syncthreads();
    }
    if (tid == 0) bsum[bi] = red[0];
}

// ---------------- merged scan of block sums ----------------
__global__ __launch_bounds__(128) void scanb2_kernel(int* __restrict__ bsum_pm,
                                                     int* __restrict__ bsum_mt,
                                                     int* __restrict__ bsum_mk) {
    __shared__ int s[128];
    const int tid = threadIdx.x;
    int* bsum = (blockIdx.x == 0) ? bsum_pm : ((blockIdx.x == 1) ? bsum_mt : bsum_mk);
    const int nb = (blockIdx.x == 0) ? 5 : 98;
    int v = (tid < nb) ? bsum[tid] : 0;
    s[tid] = v;
    __syncthreads();
    for (int off = 1; off < 128; off <<= 1) {
        int t = (tid >= off) ? s[tid - off] : 0;
        __syncthreads();
        s[tid] += t;
        __syncthreads();
    }
    if (tid < nb) bsum[tid] = (tid > 0) ? s[tid - 1] : 0;
    if (tid == 0) bsum[nb] = s[nb - 1];   // total (mk: unique row count)
}

// ---------------- merged emit: rowptrs + compact list + inv map ----------------
__global__ __launch_bounds__(256) void emit2_kernel(const int* __restrict__ deg_pm,
                                                    const int* __restrict__ deg_mt,
                                                    const int* __restrict__ mark,
                                                    const int* __restrict__ bsum_pm,
                                                    const int* __restrict__ bsum_mt,
                                                    const int* __restrict__ bsum_mk,
                                                    int* __restrict__ rp_pm,
                                                    int* __restrict__ rp_mt,
                                                    int* __restrict__ list,
                                                    int* __restrict__ inv) {
    __shared__ int tsum[256];
    const int tid = threadIdx.x;
    const int* deg; const int* bsum; int* rp; int n, nb, bi, mode;
    if (blockIdx.x < 5) { deg = deg_pm; bsum = bsum_pm; rp = rp_pm; n = NMHC; nb = 5; bi = blockIdx.x; mode = 0; }
    else if (blockIdx.x < 103) { deg = deg_mt; bsum = bsum_mt; rp = rp_mt; n = NTCR; nb = 98; bi = blockIdx.x - 5; mode = 0; }
    else { deg = mark; bsum = bsum_mk; rp = nullptr; n = NTCR; nb = 98; bi = blockIdx.x - 103; mode = 1; }
    const int i0 = bi * 1024 + tid * 4;
    int4 v = make_int4(0, 0, 0, 0);
    if (i0 + 3 < n) v = *(const int4*)(deg + i0);
    else if (i0 < n) {
        int t[4] = {0, 0, 0, 0};
        for (int j = 0; j < 4 && i0 + j < n; j++) t[j] = deg[i0 + j];
        v = make_int4(t[0], t[1], t[2], t[3]);
    }
    tsum[tid] = v.x + v.y + v.z + v.w;
    __syncthreads();
    for (int off = 1; off < 256; off <<= 1) {
        int t = (tid >= off) ? tsum[tid - off] : 0;
        __syncthreads();
        tsum[tid] += t;
        __syncthreads();
    }
    int ex = ((tid > 0) ? tsum[tid - 1] : 0) + bsum[bi];
    if (mode == 0) {
        if (i0 + 3 < n) {
            int r1 = ex + v.x, r2 = r1 + v.y, r3 = r2 + v.z;
            *(int4*)(rp + i0) = make_int4(ex, r1, r2, r3);
        } else if (i0 < n) {
            int r = ex;
            int vv[4] = {v.x, v.y, v.z, v.w};
            for (int j = 0; j < 4 && i0 + j < n; j++) { rp[i0 + j] = r; r += vv[j]; }
        }
        if (bi == 0 && tid == 0) rp[n] = bsum[nb];
    } else {
        int p = ex;
        int vv[4] = {v.x, v.y, v.z, v.w};
#pragma unroll
        for (int j = 0; j < 4; j++) {
            if (i0 + j < n && vv[j]) { list[p] = i0 + j; inv[i0 + j] = p; p++; }
        }
    }
}

// ---------------- merged CSR fill ----------------
__global__ void fill2_kernel(const int* __restrict__ src_pm, const int* __restrict__ dst_pm,
                             const int* __restrict__ src_mt, const int* __restrict__ dst_mt,
                             const int* __restrict__ rp_pm, int* __restrict__ cur_pm, int* __restrict__ csr_pm,
                             const int* __restrict__ rp_mt, int* __restrict__ cur_mt, int* __restrict__ csr_mt) {
    int t = blockIdx.x * blockDim.x + threadIdx.x;
    if (t < EPM) {
        int d = dst_pm[t];
        int pos = atomicAdd(&cur_pm[d], 1);
        csr_pm[rp_pm[d] + pos] = src_pm[t];
    } else if (t < EPM + EMT) {
        int t2 = t - EPM;
        int d = dst_mt[t2];
        int pos = atomicAdd(&cur_mt[d], 1);
        csr_mt[rp_mt[d] + pos] = src_mt[t2];
    }
}

// ---------------- merged: pm gather + Hp GEMM + pt remap ----------------
__global__ __launch_bounds__(256, 2) void gph_kernel(
    const int* __restrict__ rp, const int* __restrict__ csr_src,
    const float* __restrict__ X, ushort* __restrict__ A1, ushort* __restrict__ A2,
    const float* __restrict__ emb_pep, const ushort* __restrict__ Wcomp,
    const float* __restrict__ bp, ushort* __restrict__ Hp,
    const int* __restrict__ pack_tcr, const int* __restrict__ inv, int* __restrict__ pt_c) {
    __shared__ ushort Als[128 * RS];
    __shared__ ushort Wls[128 * RS];
    const int tid = threadIdx.x;
    const int b = blockIdx.x;
    if (b < 625) {
        // gatherpm: 8 rows per block
        const int r = b * 8 + (tid >> 5);
        const int lane = tid & 31;
        if (r >= NMHC) return;
        const int e0 = rp[r], e1 = rp[r + 1];
        float4 s = make_float4(0.f, 0.f, 0.f, 0.f);
        for (int e = e0; e < e1; e++) {
            const int sidx = csr_src[e];
            float4 v = ((const float4*)(X + (long)sidx * 128))[lane];
            s.x += v.x; s.y += v.y; s.z += v.z; s.w += v.w;
        }
        float sc = 1.f / fmaxf((float)(e1 - e0), 1.f);
        ushort4 o = make_ushort4(f2bf(s.x * sc), f2bf(s.y * sc), f2bf(s.z * sc), f2bf(s.w * sc));
        *(ushort4*)(A1 + (size_t)r * 256 + lane * 4) = o;
        *(ushort4*)(A2 + (size_t)r * 384 + lane * 4) = o;
    } else if (b < 939) {
        int v = b - 625;                       // 0..313
        out_tile<128, true, true>(Als, Wls, tid, v % 157, v / 157, NPEP,
                                  emb_pep, Wcomp, bp, Hp);
    } else {
        int i = (b - 939) * 256 + tid;
        if (i < BB) pt_c[i] = inv[pack_tcr[i]];
    }
}

// ---------------- bf16 MFMA fused GEMM (mhc layers): dual bf16 outputs ----------------
template <int K, int NB0, bool RELU0, bool G2>
__global__ __launch_bounds__(256, 2) void mfma_fused_kernel(
    int M, const ushort* __restrict__ A, const ushort* __restrict__ W,
    const float* __restrict__ bias,
    ushort* __restrict__ out0, int s0, ushort* __restrict__ out1) {
    __shared__ ushort Als[128 * RS];
    __shared__ ushort Wls[128 * RS];
    const int tid = threadIdx.x;
    const int m0 = blockIdx.x * 128, n0 = blockIdx.y * 128;
    const int lane = tid & 63, w = tid >> 6;
    const int wm = w >> 1, wn = w & 1;
    const int m16 = lane & 15, q = lane >> 4;

    f32x4 acc[4][4] = {};

    for (int k0 = 0; k0 < K; k0 += 32) {
        bf16x8 a_st[2], w_st[2];
#pragma unroll
        for (int r = 0; r < 2; r++) {
            int chunk = tid + r * 256;
            int row = chunk >> 2, off = (chunk & 3) * 8;
            int ga = min(m0 + row, M - 1);
            a_st[r] = *(const bf16x8*)(A + (size_t)ga * K + k0 + off);
            w_st[r] = *(const bf16x8*)(W + (size_t)(n0 + row) * K + k0 + off);
        }
        __syncthreads();
#pragma unroll
        for (int r = 0; r < 2; r++) {
            int chunk = tid + r * 256;
            int row = chunk >> 2, off = (chunk & 3) * 8;
            *(bf16x8*)(&Als[row * RS + off]) = a_st[r];
            *(bf16x8*)(&Wls[row * RS + off]) = w_st[r];
        }
        __syncthreads();
        bf16x8 af[4], bf[4];
#pragma unroll
        for (int t = 0; t < 4; t++) {
            af[t] = *(const bf16x8*)(&Als[(wm * 64 + t * 16 + m16) * RS + q * 8]);
            bf[t] = *(const bf16x8*)(&Wls[(wn * 64 + t * 16 + m16) * RS + q * 8]);
        }
#pragma unroll
        for (int mt = 0; mt < 4; mt++)
#pragma unroll
            for (int nt = 0; nt < 4; nt++)
                acc[mt][nt] = __builtin_amdgcn_mfma_f32_16x16x32_bf16(af[mt], bf[nt], acc[mt][nt], 0, 0, 0);
    }

    const bool g1 = G2 && ((int)blockIdx.y >= NB0);
#pragma unroll
    for (int mt = 0; mt < 4; mt++) {
#pragma unroll
        for (int i = 0; i < 4; i++) {
            int row = m0 + wm * 64 + mt * 16 + q * 4 + i;
            if (row >= M) continue;
#pragma unroll
            for (int nt = 0; nt < 4; nt++) {
                int col = n0 + wn * 64 + nt * 16 + m16;
                float v = acc[mt][nt][i];
                if (!g1) {
                    v += bias[col];
                    if (RELU0) v = fmaxf(v, 0.f);
                    out0[(size_t)row * s0 + col] = f2bf(v);
                } else {
                    out1[(size_t)row * 256 + (col - NB0 * 128)] = f2bf(v);
                }
            }
        }
    }
}

// ---------------- fused TCR chain (compact rows, 32-row tiles) + Hm GEMM ----------------
// Block b < 1563 : tcr tile -> Ht_c (COMPACT rows, coalesced streaming writes)
// Block b >= 1563: Hm = mhc2 @ W1b^T tile
__global__ __launch_bounds__(256, 3) void tcrhm_kernel(
    const int* __restrict__ nrowsp, const int* __restrict__ list,
    const int* __restrict__ rp, const int* __restrict__ csr_src,
    const ushort* __restrict__ Z1, const ushort* __restrict__ Z2,
    const float* __restrict__ emb_tcr,
    const ushort* __restrict__ Wr1, const ushort* __restrict__ Wr2,
    const ushort* __restrict__ W1c,
    const float* __restrict__ bl1, const float* __restrict__ bl2,
    ushort* __restrict__ Ht_c,
    const ushort* __restrict__ mhc2, const ushort* __restrict__ W1b,
    ushort* __restrict__ Hm) {
    union SM {
        struct { ushort B[32 * RS2]; ushort A1[32 * RS2]; ushort A2[32 * RS2]; } t;  // 50688 B
        struct { ushort Als[128 * RS]; ushort Wls[128 * RS]; } g;
    };
    __shared__ SM sm;
    const int tid = threadIdx.x;

    if (blockIdx.x >= 1563) {
        int v = blockIdx.x - 1563;             // 0..79
        out_tile<256, false, false>(sm.g.Als, sm.g.Wls, tid, v % 40, v / 40, NMHC,
                                    mhc2, W1b, nullptr, Hm);
        return;
    }

    const int M = nrowsp[0];
    const int m0 = blockIdx.x * 32;
    if (m0 >= M) return;
    const int lane = tid & 63, w = tid >> 6;   // wave w: cols w*64..w*64+63
    const int m16 = lane & 15, q = lane >> 4;

    // ---- stage 0: emb_tcr rows f32->bf16 -> B (RS1) ----
#pragma unroll
    for (int r = 0; r < 4; r++) {
        int chunk = tid + r * 256;             // 1024 chunks: 32 rows x 32 float4
        int row = chunk >> 5, c4 = (chunk & 31) * 4;
        int grow = list[min(m0 + row, M - 1)];
        float4 v = *(const float4*)(emb_tcr + (size_t)grow * 128 + c4);
        *(ushort4*)(&sm.t.B[row * RS1 + c4]) = f4bf(v);
    }

    // ---- neighbor-mean gather -> A1, A2 (pre-scaled); sidx broadcast via shfl ----
    {
        const int g = tid >> 5, gl = tid & 31;
        for (int rr = g; rr < 32; rr += 8) {
            int cr = min(m0 + rr, M - 1);
            int orig = list[cr];
            int e0 = rp[orig], e1 = rp[orig + 1];
            int deg = e1 - e0;
            float s1[8] = {}, s2[8] = {};
            // parallel csr fetch: lane gl holds csr[e0+gl]; broadcast per edge
            int sidx_l = (gl < deg) ? csr_src[e0 + gl] : 0;
            int dn = min(deg, 32);
            for (int e = 0; e < dn; e++) {
                int sidx = __shfl(sidx_l, e, 32);
                uint4 u1 = *(const uint4*)(Z1 + (size_t)sidx * 256 + gl * 8);
                uint4 u2 = *(const uint4*)(Z2 + (size_t)sidx * 256 + gl * 8);
                float x, y;
                bf2x2(u1.x, x, y); s1[0] += x; s1[1] += y;
                bf2x2(u1.y, x, y); s1[2] += x; s1[3] += y;
                bf2x2(u1.z, x, y); s1[4] += x; s1[5] += y;
                bf2x2(u1.w, x, y); s1[6] += x; s1[7] += y;
                bf2x2(u2.x, x, y); s2[0] += x; s2[1] += y;
                bf2x2(u2.y, x, y); s2[2] += x; s2[3] += y;
                bf2x2(u2.z, x, y); s2[4] += x; s2[5] += y;
                bf2x2(u2.w, x, y); s2[6] += x; s2[7] += y;
            }
            for (int e = e0 + 32; e < e1; e++) {     // rare deg>32 tail
                int sidx = csr_src[e];
                uint4 u1 = *(const uint4*)(Z1 + (size_t)sidx * 256 + gl * 8);
                uint4 u2 = *(const uint4*)(Z2 + (size_t)sidx * 256 + gl * 8);
                float x, y;
                bf2x2(u1.x, x, y); s1[0] += x; s1[1] += y;
                bf2x2(u1.y, x, y); s1[2] += x; s1[3] += y;
                bf2x2(u1.z, x, y); s1[4] += x; s1[5] += y;
                bf2x2(u1.w, x, y); s1[6] += x; s1[7] += y;
                bf2x2(u2.x, x, y); s2[0] += x; s2[1] += y;
                bf2x2(u2.y, x, y); s2[2] += x; s2[3] += y;
                bf2x2(u2.z, x, y); s2[4] += x; s2[5] += y;
                bf2x2(u2.w, x, y); s2[6] += x; s2[7] += y;
            }
            float es = 1.f / fmaxf((float)deg, 1.f);
            uint4 w1, w2;
            w1.x = (unsigned)f2bf(s1[0] * es) | ((unsigned)f2bf(s1[1] * es) << 16);
            w1.y = (unsigned)f2bf(s1[2] * es) | ((unsigned)f2bf(s1[3] * es) << 16);
            w1.z = (unsigned)f2bf(s1[4] * es) | ((unsigned)f2bf(s1[5] * es) << 16);
            w1.w = (unsigned)f2bf(s1[6] * es) | ((unsigned)f2bf(s1[7] * es) << 16);
            w2.x = (unsigned)f2bf(s2[0] * es) | ((unsigned)f2bf(s2[1] * es) << 16);
            w2.y = (unsigned)f2bf(s2[2] * es) | ((unsigned)f2bf(s2[3] * es) << 16);
            w2.z = (unsigned)f2bf(s2[4] * es) | ((unsigned)f2bf(s2[5] * es) << 16);
            w2.w = (unsigned)f2bf(s2[6] * es) | ((unsigned)f2bf(s2[7] * es) << 16);
            *(uint4*)(&sm.t.A1[rr * RS2 + gl * 8]) = w1;
            *(uint4*)(&sm.t.A2[rr * RS2 + gl * 8]) = w2;
        }
    }
    __syncthreads();

    // ---- stage 1a: T1 = relu(etc @ Wr1^T + bl1 + A1) ----
    {
        f32x4 acc[2][4] = {};
        for (int k0 = 0; k0 < 128; k0 += 32) {
            bf16x8 af[2], bf[4];
#pragma unroll
            for (int t = 0; t < 2; t++)
                af[t] = *(const bf16x8*)(&sm.t.B[(t * 16 + m16) * RS1 + k0 + q * 8]);
#pragma unroll
            for (int t = 0; t < 4; t++)
                bf[t] = *(const bf16x8*)(Wr1 + (size_t)(w * 64 + t * 16 + m16) * 128 + k0 + q * 8);
#pragma unroll
            for (int mt = 0; mt < 2; mt++)
#pragma unroll
                for (int nt = 0; nt < 4; nt++)
                    acc[mt][nt] = __builtin_amdgcn_mfma_f32_16x16x32_bf16(af[mt], bf[nt], acc[mt][nt], 0, 0, 0);
        }
        __syncthreads();
#pragma unroll
        for (int mt = 0; mt < 2; mt++)
#pragma unroll
            for (int i = 0; i < 4; i++) {
                int lr = mt * 16 + q * 4 + i;
#pragma unroll
                for (int nt = 0; nt < 4; nt++) {
                    int col = w * 64 + nt * 16 + m16;
                    float v = acc[mt][nt][i] + bl1[col] + bf2f(sm.t.A1[lr * RS2 + col]);
                    sm.t.B[lr * RS2 + col] = f2bf(fmaxf(v, 0.f));
                }
            }
    }
    __syncthreads();

    // ---- stage 1b: T = relu(T1 @ Wr2^T + bl2 + A2) ----
    {
        f32x4 acc[2][4] = {};
        for (int k0 = 0; k0 < 256; k0 += 32) {
            bf16x8 af[2], bf[4];
#pragma unroll
            for (int t = 0; t < 2; t++)
                af[t] = *(const bf16x8*)(&sm.t.B[(t * 16 + m16) * RS2 + k0 + q * 8]);
#pragma unroll
            for (int t = 0; t < 4; t++)
                bf[t] = *(const bf16x8*)(Wr2 + (size_t)(w * 64 + t * 16 + m16) * 256 + k0 + q * 8);
#pragma unroll
            for (int mt = 0; mt < 2; mt++)
#pragma unroll
                for (int nt = 0; nt < 4; nt++)
                    acc[mt][nt] = __builtin_amdgcn_mfma_f32_16x16x32_bf16(af[mt], bf[nt], acc[mt][nt], 0, 0, 0);
        }
        __syncthreads();
#pragma unroll
        for (int mt = 0; mt < 2; mt++)
#pragma unroll
            for (int i = 0; i < 4; i++) {
                int lr = mt * 16 + q * 4 + i;
#pragma unroll
                for (int nt = 0; nt < 4; nt++) {
                    int col = w * 64 + nt * 16 + m16;
                    float v = acc[mt][nt][i] + bl2[col] + bf2f(sm.t.A2[lr * RS2 + col]);
                    sm.t.B[lr * RS2 + col] = f2bf(fmaxf(v, 0.f));
                }
            }
    }
    __syncthreads();

    // ---- stage 2: Ht_tile = T @ W1c^T -> B ----
    {
        f32x4 acc[2][4] = {};
        for (int k0 = 0; k0 < 256; k0 += 32) {
            bf16x8 af[2], bf[4];
#pragma unroll
            for (int t = 0; t < 2; t++)
                af[t] = *(const bf16x8*)(&sm.t.B[(t * 16 + m16) * RS2 + k0 + q * 8]);
#pragma unroll
            for (int t = 0; t < 4; t++)
                bf[t] = *(const bf16x8*)(W1c + (size_t)(w * 64 + t * 16 + m16) * 256 + k0 + q * 8);
#pragma unroll
            for (int mt = 0; mt < 2; mt++)
#pragma unroll
                for (int nt = 0; nt < 4; nt++)
                    acc[mt][nt] = __builtin_amdgcn_mfma_f32_16x16x32_bf16(af[mt], bf[nt], acc[mt][nt], 0, 0, 0);
        }
        __syncthreads();
#pragma unroll
        for (int mt = 0; mt < 2; mt++)
#pragma unroll
            for (int i = 0; i < 4; i++) {
                int lr = mt * 16 + q * 4 + i;
#pragma unroll
                for (int nt = 0; nt < 4; nt++) {
                    int col = w * 64 + nt * 16 + m16;
                    sm.t.B[lr * RS2 + col] = f2bf(acc[mt][nt][i]);
                }
            }
    }
    __syncthreads();

    // coalesced COMPACT writeback: consecutive rows -> streaming stores
#pragma unroll
    for (int r = 0; r < 4; r++) {
        int chunk = tid + r * 256;             // 1024 chunks: 32 rows x 32 uint4
        int row = chunk >> 5, c8 = (chunk & 31) * 8;
        if (m0 + row < M)
            *(uint4*)(Ht_c + (size_t)(m0 + row) * 256 + c8) = *(const uint4*)(&sm.t.B[row * RS2 + c8]);
    }
}

// ---------------- combine: out[i] = relu(Hp[pp]+Hm[pm]+Ht_c[pt_c]+b1) . W2 + b2 ----------------
__global__ __launch_bounds__(256) void combine_kernel(
    const ushort* __restrict__ Hp, const ushort* __restrict__ Hm, const ushort* __restrict__ Ht,
    const int* __restrict__ pp, const int* __restrict__ pm, const int* __restrict__ pt_c,
    const float* __restrict__ b1, const float* __restrict__ W2, const float* __restrict__ b2,
    float* __restrict__ out) {
    const int tid = threadIdx.x;
    const int lane = tid & 63, w = tid >> 6;
    const int c = lane * 4;
    const float4 b1v = *(const float4*)(b1 + c);
    const float4 w2v = *(const float4*)(W2 + c);
    const float b2v = b2[0];
    const int base = blockIdx.x * 32 + w * 8;
#pragma unroll
    for (int t = 0; t < 8; t++) {
        int i = base + t;
        if (i >= BB) return;
        int ra = pp[i], rb = pm[i], rc = pt_c[i];
        ushort4 ua = *(const ushort4*)(Hp + (size_t)ra * 256 + c);
        ushort4 ub = *(const ushort4*)(Hm + (size_t)rb * 256 + c);
        ushort4 uc = *(const ushort4*)(Ht + (size_t)rc * 256 + c);
        float h0 = fmaxf(bf2f(ua.x) + bf2f(ub.x) + bf2f(uc.x) + b1v.x, 0.f);
        float h1 = fmaxf(bf2f(ua.y) + bf2f(ub.y) + bf2f(uc.y) + b1v.y, 0.f);
        float h2 = fmaxf(bf2f(ua.z) + bf2f(ub.z) + bf2f(uc.z) + b1v.z, 0.f);
        float h3 = fmaxf(bf2f(ua.w) + bf2f(ub.w) + bf2f(uc.w) + b1v.w, 0.f);
        float p = h0 * w2v.x + h1 * w2v.y + h2 * w2v.z + h3 * w2v.w;
#pragma unroll
        for (int off = 32; off > 0; off >>= 1) p += __shfl_down(p, off);
        if (lane == 0) out[i] = p + b2v;
    }
}

// ---------------- launch ----------------
extern "C" void kernel_launch(void* const* d_in, const int* in_sizes, int n_in,
                              void* d_out, int out_size, void* d_ws, size_t ws_size,
                              hipStream_t stream) {
    const float* emb_pep = (const float*)d_in[0];
    const float* emb_mhc = (const float*)d_in[1];
    const float* emb_tcr = (const float*)d_in[2];
    const int* src_pm = (const int*)d_in[3];
    const int* dst_pm = (const int*)d_in[4];
    const int* src_mt = (const int*)d_in[5];
    const int* dst_mt = (const int*)d_in[6];
    const int* pack_pep = (const int*)d_in[7];
    const int* pack_mhc = (const int*)d_in[8];
    const int* pack_tcr = (const int*)d_in[9];
    const float* l1_pm_Wl = (const float*)d_in[10];
    const float* l1_pm_bl = (const float*)d_in[11];
    const float* l1_pm_Wr = (const float*)d_in[12];
    const float* l1_mt_Wl = (const float*)d_in[13];
    const float* l1_mt_bl = (const float*)d_in[14];
    const float* l1_mt_Wr = (const float*)d_in[15];
    const float* l2_pm_Wl = (const float*)d_in[16];
    const float* l2_pm_bl = (const float*)d_in[17];
    const float* l2_pm_Wr = (const float*)d_in[18];
    const float* l2_mt_Wl = (const float*)d_in[19];
    const float* l2_mt_bl = (const float*)d_in[20];
    const float* l2_mt_Wr = (const float*)d_in[21];
    const float* proj_W = (const float*)d_in[22];
    const float* proj_b = (const float*)d_in[23];
    const float* head_W1 = (const float*)d_in[24];
    const float* head_b1 = (const float*)d_in[25];
    const float* head_W2 = (const float*)d_in[26];
    const float* head_b2 = (const float*)d_in[27];
    float* out = (float*)d_out;

    // ---------------- workspace layout ----------------
    int* ib = (int*)d_ws;
    int* deg_pm = ib;                 // 5000
    int* cur_pm = ib + 5000;          // 5000
    int* deg_mt = ib + 10000;         // 100000
    int* cur_mt = ib + 110000;        // 100000
    int* mark   = ib + 210000;        // 100000  [zero region: first 310000 ints]
    int* rp_pm  = ib + 310000;        // 5001 (pad 5008)
    int* rp_mt  = ib + 315008;        // 100001 (pad 100008)
    int* csr_pm = ib + 415016;        // 200000
    int* csr_mt = ib + 615016;        // 400000
    int* bsum_pm = ib + 1015016;      // 160
    int* bsum_mt = ib + 1015176;      // 160
    int* bsum_mk = ib + 1015336;      // 160  (count at bsum_mk[98])
    int* list    = ib + 1015496;      // 50048 -> 1065544
    int* inv     = ib + 1065544;      // 100000 -> 1165544
    int* pt_c    = ib + 1165544;      // 50048 -> 1215592

    float* f = (float*)(ib + 1215592);
    float* bp = f;                    // 256

    ushort* u = (ushort*)(f + 256);
    ushort* Wcat1_b = u;              // 131072
    ushort* Wcat2_b = u + 131072;     // 196608
    ushort* W1b_b   = u + 327680;     // 65536
    ushort* W1c_b   = u + 393216;     // 65536
    ushort* Wcomp_b = u + 458752;     // 32768
    ushort* Wr1_b   = u + 491520;     // 32768
    ushort* Wr2_b   = u + 524288;     // 65536
    ushort* Acat1   = u + 589824;     // 1280000
    ushort* Acat2   = u + 1869824;    // 1920000
    ushort* Zb1     = u + 3789824;    // 1280000
    ushort* Zb2     = u + 5069824;    // 1280000
    ushort* mhc2_b  = u + 6349824;    // 1280000
    ushort* Hp_b    = u + 7629824;    // 5120000
    ushort* Hm_b    = u + 12749824;   // 1280000
    ushort* Ht_c    = u + 14029824;   // 12800000 (50000x256 compact) -> 26829824 (~59 MB)

    // 1. prep
    prep_kernel<<<2688, 256, 0, stream>>>(
        ib,
        (const float4*)l1_mt_Wr, (ushort4*)Wr1_b,
        (const float4*)l2_mt_Wr, (ushort4*)Wr2_b,
        head_W1, (ushort4*)W1b_b, (ushort4*)W1c_b,
        l1_pm_Wl, l1_pm_Wr, l1_mt_Wl, Wcat1_b,
        l2_pm_Wl, l2_pm_Wr, l2_mt_Wl, Wcat2_b,
        (const float4*)emb_mhc, Acat1,
        proj_W, proj_b, Wcomp_b, bp);

    // 2-6. CSR build + compaction
    hist2_kernel<<<(EPM + EMT + BB + 255) / 256, 256, 0, stream>>>(
        dst_pm, dst_mt, pack_tcr, deg_pm, deg_mt, mark);
    blocksum2_kernel<<<201, 256, 0, stream>>>(deg_pm, deg_mt, mark, bsum_pm, bsum_mt, bsum_mk);
    scanb2_kernel<<<3, 128, 0, stream>>>(bsum_pm, bsum_mt, bsum_mk);
    emit2_kernel<<<201, 256, 0, stream>>>(deg_pm, deg_mt, mark, bsum_pm, bsum_mt, bsum_mk,
                                          rp_pm, rp_mt, list, inv);
    fill2_kernel<<<(EPM + EMT + 255) / 256, 256, 0, stream>>>(
        src_pm, dst_pm, src_mt, dst_mt, rp_pm, cur_pm, csr_pm, rp_mt, cur_mt, csr_mt);

    // 7. merged: pm gather + Hp GEMM + pt remap
    gph_kernel<<<1135, 256, 0, stream>>>(
        rp_pm, csr_pm, emb_pep, Acat1, Acat2,
        emb_pep, Wcomp_b, bp, Hp_b,
        pack_tcr, inv, pt_c);

    // 8-9. mhc layers
    mfma_fused_kernel<256, 2, true, true><<<dim3((NMHC + 127) / 128, 4), 256, 0, stream>>>(
        NMHC, Acat1, Wcat1_b, l1_pm_bl, Acat2 + 128, 384, Zb1);
    mfma_fused_kernel<384, 2, true, true><<<dim3((NMHC + 127) / 128, 4), 256, 0, stream>>>(
        NMHC, Acat2, Wcat2_b, l2_pm_bl, mhc2_b, 256, Zb2);

    // 10. fused tcr chain (compact Ht) + Hm tiles
    tcrhm_kernel<<<1563 + 80, 256, 0, stream>>>(
        bsum_mk + 98, list, rp_mt, csr_mt, Zb1, Zb2, emb_tcr,
        Wr1_b, Wr2_b, W1c_b, l1_mt_bl, l2_mt_bl, Ht_c,
        mhc2_b, W1b_b, Hm_b);

    // 11. combine
    combine_kernel<<<(BB + 31) / 32, 256, 0, stream>>>(
        Hp_b, Hm_b, Ht_c, pack_pep, pack_mhc, pt_c,
        head_b1, head_W2, head_b2, out);
}